// Round 1
// baseline (706.364 us; speedup 1.0000x reference)
//
#include <hip/hip_runtime.h>
#include <hip/hip_bf16.h>
#include <cstdint>
#include <cstddef>

typedef __attribute__((ext_vector_type(4))) float floatx4;
typedef __attribute__((ext_vector_type(8))) short shortx8;

typedef __attribute__((address_space(1))) void gvoid;
typedef __attribute__((address_space(3))) void lvoid;

#define LOG2E 1.4426950408889634f

__device__ inline __hip_bfloat16 f2b(float x) { return __float2bfloat16(x); }
__device__ inline float b2f(__hip_bfloat16 x) { return __bfloat162float(x); }
__device__ inline short f2bs(float x) {
  __hip_bfloat16 h = __float2bfloat16(x);
  return *reinterpret_cast<short*>(&h);
}

template <typename T> __device__ inline T cvt_out(float x);
template <> __device__ inline float cvt_out<float>(float x) { return x; }
template <> __device__ inline __hip_bfloat16 cvt_out<__hip_bfloat16>(float x) { return __float2bfloat16(x); }

// ---------------- elementwise f32 -> bf16 ----------------
__global__ void cvt_f32_bf16(const float* __restrict__ in, __hip_bfloat16* __restrict__ out, int n) {
  int i = (blockIdx.x * blockDim.x + threadIdx.x) * 4;
  if (i >= n) return;
  float4 v = *(const float4*)(in + i);
  __hip_bfloat16 o[4] = { f2b(v.x), f2b(v.y), f2b(v.z), f2b(v.w) };
  *(ushort4*)(out + i) = *(const ushort4*)o;
}

// ---------------- [K][N] f32 -> [N][K] bf16 (tiled transpose) ----------------
__global__ void transpose_cvt(const float* __restrict__ in, __hip_bfloat16* __restrict__ out, int K, int N) {
  __shared__ float tile[32][33];
  int n0 = blockIdx.x * 32, k0 = blockIdx.y * 32;
  int tx = threadIdx.x, ty = threadIdx.y;  // 32 x 8
#pragma unroll
  for (int i = 0; i < 4; i++)
    tile[ty + i * 8][tx] = in[(size_t)(k0 + ty + i * 8) * N + n0 + tx];
  __syncthreads();
#pragma unroll
  for (int i = 0; i < 4; i++)
    out[(size_t)(n0 + ty + i * 8) * K + k0 + tx] = f2b(tile[tx][ty + i * 8]);
}

// ---------------- bf16 GEMM: C[M][N] = A[M][K] * Bt[N][K]^T ----------------
// 128x128 tile, BK=32, 4 waves (2x2 of 64x64), 16x16x32 bf16 MFMA,
// global_load_lds width-16 staging (m97 structure).
template <typename OutT>
__global__ __launch_bounds__(256) void gemm_bt(
    const __hip_bfloat16* __restrict__ A,
    const __hip_bfloat16* __restrict__ Bt,
    OutT* __restrict__ C, int M, int N, int K) {
  __shared__ short lA[128 * 32];
  __shared__ short lB[128 * 32];
  const int m0 = blockIdx.x * 128, n0 = blockIdx.y * 128;
  const int t = threadIdx.x;
  const int l = t & 63;
  const int w = t >> 6;
  const int wm = (w & 1) * 64, wn = (w >> 1) * 64;
  const int lr = l & 15, lq = l >> 4;
  floatx4 acc[4][4] = {};

  for (int kt = 0; kt < K; kt += 32) {
    __syncthreads();
#pragma unroll
    for (int j = 0; j < 2; j++) {
      int flat = j * 2048 + t * 8;  // element index into 128x32 tile
      const __hip_bfloat16* srcA = A + (size_t)(m0 + (flat >> 5)) * K + kt + (flat & 31);
      __builtin_amdgcn_global_load_lds((gvoid*)srcA, (lvoid*)&lA[flat], 16, 0, 0);
      const __hip_bfloat16* srcB = Bt + (size_t)(n0 + (flat >> 5)) * K + kt + (flat & 31);
      __builtin_amdgcn_global_load_lds((gvoid*)srcB, (lvoid*)&lB[flat], 16, 0, 0);
    }
    __syncthreads();
    shortx8 af[4], bfr[4];
#pragma unroll
    for (int mi = 0; mi < 4; mi++)
      af[mi] = *(const shortx8*)&lA[(wm + mi * 16 + lr) * 32 + lq * 8];
#pragma unroll
    for (int ni = 0; ni < 4; ni++)
      bfr[ni] = *(const shortx8*)&lB[(wn + ni * 16 + lr) * 32 + lq * 8];
#pragma unroll
    for (int mi = 0; mi < 4; mi++)
#pragma unroll
      for (int ni = 0; ni < 4; ni++)
        acc[mi][ni] = __builtin_amdgcn_mfma_f32_16x16x32_bf16(af[mi], bfr[ni], acc[mi][ni], 0, 0, 0);
  }
#pragma unroll
  for (int mi = 0; mi < 4; mi++)
#pragma unroll
    for (int ni = 0; ni < 4; ni++) {
      int row = m0 + wm + mi * 16 + lq * 4;
      int col = n0 + wn + ni * 16 + lr;
#pragma unroll
      for (int r = 0; r < 4; r++)
        C[(size_t)(row + r) * N + col] = cvt_out<OutT>(acc[mi][ni][r]);
    }
}

// ---------------- in-place RoPE on a 64-dim head slice ----------------
// qkv: [4096 rows][stride], head slice at head*64; pos = row % 2048
__global__ void rope_kernel(__hip_bfloat16* __restrict__ q, int stride) {
  int i = threadIdx.x;                       // 0..31
  int row = blockIdx.x * 8 + threadIdx.y;    // 0..4095
  int head = blockIdx.y;
  int pos = row & 2047;
  float freq = (float)pos * exp2f(-(float)i * (13.287712379549449f / 32.0f));
  float s, c;
  s = sinf(freq);
  c = cosf(freq);
  __hip_bfloat16* p = q + (size_t)row * stride + head * 64 + i;
  float x1 = b2f(p[0]), x2 = b2f(p[32]);
  p[0]  = f2b(x1 * c - x2 * s);
  p[32] = f2b(x2 * c + x1 * s);
}

// ---------------- V slice of QKV -> Vt [B][NKV][64][2048] ----------------
__global__ void v_transpose(const __hip_bfloat16* __restrict__ QKV, __hip_bfloat16* __restrict__ Vt) {
  int idx = blockIdx.x * 256 + threadIdx.x;  // over 2*2048*512
  int col = idx & 511, row = idx >> 9;       // row = b*2048+s
  int b = row >> 11, s = row & 2047;
  int kvh = col >> 6, d = col & 63;
  Vt[((size_t)((b * 8 + kvh) * 64 + d) << 11) + s] = QKV[(size_t)row * 3072 + 2560 + col];
}

// ---------------- flash attention ----------------
// grid (32 qtiles, 32 heads, 2 batch); block 256 (4 waves, 16 q-rows each)
__global__ __launch_bounds__(256) void attn_kernel(
    const __hip_bfloat16* __restrict__ Q,   // [4096][3072], head slice h*64
    const __hip_bfloat16* __restrict__ K,   // [4096][3072] offset to K region, slice kvh*64
    const __hip_bfloat16* __restrict__ Vt,  // [B][NKV][64][2048]
    __hip_bfloat16* __restrict__ O) {       // [4096][2048]
  __shared__ short lQ[64 * 64];
  __shared__ short lK[64 * 64];
  __shared__ short lV[64 * 64];   // V^T tile: [d][k]
  __shared__ short lP[4][16 * 64];
  const int qt = blockIdx.x, h = blockIdx.y, b = blockIdx.z;
  const int kvh = h >> 2;
  const int t = threadIdx.x, w = t >> 6, l = t & 63;
  const int lr = l & 15, lq = l >> 4;

  // stage Q tile [64 q][64 d]
#pragma unroll
  for (int j = 0; j < 2; j++) {
    int flat = j * 2048 + t * 8;
    const __hip_bfloat16* src = Q + (size_t)(b * 2048 + qt * 64 + (flat >> 6)) * 3072 + h * 64 + (flat & 63);
    __builtin_amdgcn_global_load_lds((gvoid*)src, (lvoid*)&lQ[flat], 16, 0, 0);
  }
  __syncthreads();
  shortx8 aq0 = *(const shortx8*)&lQ[(w * 16 + lr) * 64 + lq * 8];
  shortx8 aq1 = *(const shortx8*)&lQ[(w * 16 + lr) * 64 + 32 + lq * 8];

  floatx4 oacc[4] = {};
  float m_run[4] = {-1e30f, -1e30f, -1e30f, -1e30f};
  float l_run[4] = {0.f, 0.f, 0.f, 0.f};

  for (int kt = 0; kt <= qt; kt++) {
    __syncthreads();  // all waves done with previous lK/lV
#pragma unroll
    for (int j = 0; j < 2; j++) {
      int flat = j * 2048 + t * 8;
      const __hip_bfloat16* srcK = K + (size_t)(b * 2048 + kt * 64 + (flat >> 6)) * 3072 + kvh * 64 + (flat & 63);
      __builtin_amdgcn_global_load_lds((gvoid*)srcK, (lvoid*)&lK[flat], 16, 0, 0);
      const __hip_bfloat16* srcV = Vt + ((size_t)((b * 8 + kvh) * 64 + (flat >> 6)) << 11) + kt * 64 + (flat & 63);
      __builtin_amdgcn_global_load_lds((gvoid*)srcV, (lvoid*)&lV[flat], 16, 0, 0);
    }
    __syncthreads();

    // S = Q K^T for this wave's 16 q-rows x 64 k-cols
    floatx4 sacc[4] = {};
#pragma unroll
    for (int ni = 0; ni < 4; ni++) {
      shortx8 bk0 = *(const shortx8*)&lK[(ni * 16 + lr) * 64 + lq * 8];
      shortx8 bk1 = *(const shortx8*)&lK[(ni * 16 + lr) * 64 + 32 + lq * 8];
      sacc[ni] = __builtin_amdgcn_mfma_f32_16x16x32_bf16(aq0, bk0, sacc[ni], 0, 0, 0);
      sacc[ni] = __builtin_amdgcn_mfma_f32_16x16x32_bf16(aq1, bk1, sacc[ni], 0, 0, 0);
    }

    const int qbase = qt * 64 + w * 16 + lq * 4;
    const int kbase = kt * 64 + lr;
    float alpha[4];
#pragma unroll
    for (int r = 0; r < 4; r++) {
      float mx = -1e30f;
#pragma unroll
      for (int ni = 0; ni < 4; ni++) {
        float sv = sacc[ni][r] * 0.125f;
        if (kbase + ni * 16 > qbase + r) sv = -1e9f;
        sacc[ni][r] = sv;
        mx = fmaxf(mx, sv);
      }
#pragma unroll
      for (int off = 1; off < 16; off <<= 1)
        mx = fmaxf(mx, __shfl_xor(mx, off, 64));
      float mnew = fmaxf(m_run[r], mx);
      alpha[r] = exp2f((m_run[r] - mnew) * LOG2E);
      m_run[r] = mnew;
      float rs = 0.f;
#pragma unroll
      for (int ni = 0; ni < 4; ni++) {
        float p = exp2f((sacc[ni][r] - mnew) * LOG2E);
        sacc[ni][r] = p;
        rs += p;
      }
#pragma unroll
      for (int off = 1; off < 16; off <<= 1)
        rs += __shfl_xor(rs, off, 64);
      l_run[r] = l_run[r] * alpha[r] + rs;
    }

    // P (C-layout) -> per-wave LDS in A-layout [16 q][64 k]
#pragma unroll
    for (int r = 0; r < 4; r++)
#pragma unroll
      for (int ni = 0; ni < 4; ni++)
        lP[w][(lq * 4 + r) * 64 + ni * 16 + lr] = f2bs(sacc[ni][r]);
    // same-wave ds write->read: HW-ordered via lgkmcnt, no barrier needed
    shortx8 ap0 = *(const shortx8*)&lP[w][lr * 64 + lq * 8];
    shortx8 ap1 = *(const shortx8*)&lP[w][lr * 64 + 32 + lq * 8];
#pragma unroll
    for (int nj = 0; nj < 4; nj++) {
      shortx8 bv0 = *(const shortx8*)&lV[(nj * 16 + lr) * 64 + lq * 8];
      shortx8 bv1 = *(const shortx8*)&lV[(nj * 16 + lr) * 64 + 32 + lq * 8];
      floatx4 o = oacc[nj];
#pragma unroll
      for (int r = 0; r < 4; r++) o[r] *= alpha[r];
      o = __builtin_amdgcn_mfma_f32_16x16x32_bf16(ap0, bv0, o, 0, 0, 0);
      o = __builtin_amdgcn_mfma_f32_16x16x32_bf16(ap1, bv1, o, 0, 0, 0);
      oacc[nj] = o;
    }
  }

  const size_t orow = (size_t)(b * 2048 + qt * 64 + w * 16 + lq * 4);
#pragma unroll
  for (int nj = 0; nj < 4; nj++)
#pragma unroll
    for (int r = 0; r < 4; r++)
      O[(orow + r) * 2048 + h * 64 + nj * 16 + lr] = f2b(oacc[nj][r] / l_run[r]);
}

extern "C" void kernel_launch(void* const* d_in, const int* in_sizes, int n_in,
                              void* d_out, int out_size, void* d_ws, size_t ws_size,
                              hipStream_t stream) {
  (void)in_sizes; (void)n_in; (void)out_size; (void)ws_size;
  const float* hs = (const float*)d_in[0];
  // d_in[1] = attention_mask (pure causal -> synthesized), d_in[2] = position_ids (= arange)
  const float* Wq = (const float*)d_in[3];
  const float* Wk = (const float*)d_in[4];
  const float* Wv = (const float*)d_in[5];
  const float* Wo = (const float*)d_in[6];
  float* out = (float*)d_out;

  char* p = (char*)d_ws;
  auto alloc = [&](size_t elts) { __hip_bfloat16* r = (__hip_bfloat16*)p; p += elts * 2; return r; };
  __hip_bfloat16* Xb   = alloc(4096ull * 4096);       // X bf16
  __hip_bfloat16* Wt   = alloc(3072ull * 4096);       // [Wq^T; Wk^T; Wv^T] bf16
  __hip_bfloat16* Wot  = alloc(2048ull * 2048);       // Wo^T bf16
  __hip_bfloat16* QKVb = alloc(4096ull * 3072);       // fused QKV output
  __hip_bfloat16* Vtb  = alloc(2ull * 8 * 64 * 2048); // V^T per (b,kvh)
  __hip_bfloat16* Ab   = alloc(4096ull * 2048);       // attention output

  cvt_f32_bf16<<<16384, 256, 0, stream>>>(hs, Xb, 4096 * 4096);
  transpose_cvt<<<dim3(64, 128), dim3(32, 8), 0, stream>>>(Wq, Wt, 4096, 2048);
  transpose_cvt<<<dim3(16, 128), dim3(32, 8), 0, stream>>>(Wk, Wt + 2048ull * 4096, 4096, 512);
  transpose_cvt<<<dim3(16, 128), dim3(32, 8), 0, stream>>>(Wv, Wt + 2560ull * 4096, 4096, 512);
  transpose_cvt<<<dim3(64, 64), dim3(32, 8), 0, stream>>>(Wo, Wot, 2048, 2048);

  gemm_bt<__hip_bfloat16><<<dim3(32, 24), 256, 0, stream>>>(Xb, Wt, QKVb, 4096, 3072, 4096);

  rope_kernel<<<dim3(512, 32), dim3(32, 8), 0, stream>>>(QKVb, 3072);          // Q heads
  rope_kernel<<<dim3(512, 8), dim3(32, 8), 0, stream>>>(QKVb + 2048, 3072);    // K heads
  v_transpose<<<8192, 256, 0, stream>>>(QKVb, Vtb);

  attn_kernel<<<dim3(32, 32, 2), 256, 0, stream>>>(QKVb, QKVb + 2048, Vtb, Ab);

  gemm_bt<float><<<dim3(32, 16), 256, 0, stream>>>(Ab, Wot, out, 4096, 2048, 2048);
}